// Round 12
// baseline (191.669 us; speedup 1.0000x reference)
//
#include <hip/hip_runtime.h>
#include <stdint.h>

typedef unsigned short u16;
typedef unsigned int   u32;

#define B_    16
#define T_    512
#define H_    384
#define F_    384
#define DMAX_ 8
#define L_    4096     // T_*DMAX_
#define KD    1152     // 3*H_
#define M_    8192     // B_*T_

typedef __bf16 bf16x8 __attribute__((ext_vector_type(8)));
typedef float  f32x4  __attribute__((ext_vector_type(4)));

typedef __attribute__((address_space(1))) u32 gu32;
typedef __attribute__((address_space(3))) u32 lu32;

__device__ __forceinline__ void dma16(const void* g, void* l) {
    __builtin_amdgcn_global_load_lds((gu32*)(uintptr_t)g, (lu32*)(u32)(uintptr_t)l, 16, 0, 0);
}

__device__ __forceinline__ u16 f2b(float f) {
    union { float f; u32 i; } v; v.f = f;
    u32 x = v.i;
    return (u16)((x + 0x7fffu + ((x >> 16) & 1u)) >> 16);   // RNE fp32->bf16
}

// =============== prep: durmap + zeropage + repack (coalesced) + xcast ===============
// grid: [0,16) durmap; 16 zp; [17,17+1728) repack; [1745,1745+1536) xcast. block=512.
__global__ void k_prep(const float* __restrict__ td, const float* __restrict__ w1,
                       const float* __restrict__ w2, const float* __restrict__ x,
                       int* __restrict__ tmap, u16* __restrict__ Wp1,
                       u16* __restrict__ Wp2, u16* __restrict__ xb,
                       u16* __restrict__ zp) {
    int blk = blockIdx.x, tid = threadIdx.x;
    if (blk < 16) {
        __shared__ int s[T_];
        int b = blk, t = tid;
        int d = (int)roundf(expf(td[b * T_ + t]));
        if (d < 0) d = 0; if (d > DMAX_) d = DMAX_;
        int v = d;
        s[t] = v;
        __syncthreads();
        for (int off = 1; off < T_; off <<= 1) {
            int add = (t >= off) ? s[t - off] : 0;
            __syncthreads();
            v += add;
            s[t] = v;
            __syncthreads();
        }
        int end = v, start = end - d;
        for (int i = start; i < end; ++i) tmap[b * L_ + i] = t;
        int total = s[T_ - 1];
        for (int l = total + t; l < L_; l += T_) tmap[b * L_ + l] = -1;
    } else if (blk == 16) {
        zp[tid] = 0;
    } else if (blk < 17 + 1728) {
        // dst-major: coalesced 2B writes, stride-3 reads (L2-absorbed)
        int i = (blk - 17) * 512 + tid;              // [0, 2*F*KD)
        const int n = F_ * KD;
        const float* src = (i < n) ? w1 : w2;
        u16* dst         = (i < n) ? Wp1 : Wp2;
        int ii = (i < n) ? i : i - n;
        int f = ii / KD;
        int rem = ii % KD;
        int kk = rem / H_, c = rem % H_;
        dst[ii] = f2b(src[f * KD + c * 3 + kk]);
    } else {
        int v = (blk - 1745) * 512 + tid;            // [0, M*96) float4 groups
        float4 f = *(const float4*)(x + (size_t)v * 4);
        u16 o[4] = { f2b(f.x), f2b(f.y), f2b(f.z), f2b(f.w) };
        *(uint2*)(xb + (size_t)v * 4) = *(uint2*)o;
    }
}

// =============== GEMM core: BM=64, BN=384, BK=32, dbuf, 512 thr, 56 KB LDS ===============
// Per buffer: B = chunks [0,1536) (384 rows x 4 chunks), A = chunks [1536,1792).
// chunk c at elem offset c*8 (16B). 4 chunks/row: phys = (q + g(row))&3,
// g(r) = (r + (r>>2)) & 3  -> ds_read_b128 2-way bank aliasing (free).
// dbuf stride DBO2 elems. 36 K-steps (12 per tap).
#define CH2  1792
#define DBO2 14336   // CH2*8 elems (28672 B); total LDS 2*28672 = 57344 B

__device__ __forceinline__ int swz4(int q, int row) {
    return (q + row + (row >> 2)) & 3;
}

__device__ __forceinline__ void gemm_core32(u16* smem, const u16* __restrict__ src,
                                            const u16* __restrict__ Wp,
                                            const u16* __restrict__ zp,
                                            int m0, int tid, f32x4 acc[2][6]) {
    int w = tid >> 6, lane = tid & 63;
    int quad = lane >> 4, l16 = lane & 15;
    int wm = w & 1, wn = w >> 1;

    // A staging: tid<256 stages chunk 1536+tid
    const u16* abase[3];
    int adst = (1536 + tid) * 8;
    {
        int at = tid & 255;
        int rowA = at >> 2;                    // [0,64)
        int p = at & 3;
        int qlA = (p - rowA - (rowA >> 2)) & 3;     // inverse of swz4
        int arow = m0 + rowA;
        int bB = arow >> 9, tt = arow & 511;
        #pragma unroll
        for (int kk = 0; kk < 3; ++kk) {
            int ts = tt + kk - 1;
            abase[kk] = (ts >= 0 && ts < T_) ? (src + (size_t)((bB << 9) + ts) * H_ + qlA * 8)
                                             : (zp + qlA * 8);
        }
    }
    // B staging: 3 chunks/thread
    const u16* bbase[3];
    int bdst[3];
    #pragma unroll
    for (int p = 0; p < 3; ++p) {
        int idx = p * 512 + tid;               // [0,1536)
        int rowB = idx >> 2;                   // [0,384)
        int pp = idx & 3;
        int qlB = (pp - rowB - (rowB >> 2)) & 3;
        bbase[p] = Wp + (size_t)rowB * KD + qlB * 8;
        bdst[p]  = idx * 8;
    }

    // read offsets (elements)
    int aoff[2], boff[6];
    #pragma unroll
    for (int i = 0; i < 2; ++i) {
        int row = wm * 32 + i * 16 + l16;
        aoff[i] = (1536 + ((row << 2) | swz4(quad, row))) * 8;
    }
    #pragma unroll
    for (int j = 0; j < 6; ++j) {
        int row = wn * 96 + j * 16 + l16;
        boff[j] = (((row << 2) | swz4(quad, row))) * 8;
    }

    #pragma unroll
    for (int i = 0; i < 2; ++i)
        #pragma unroll
        for (int j = 0; j < 6; ++j)
            acc[i][j] = f32x4{0.f, 0.f, 0.f, 0.f};

    // stage step 0 -> buf 0
    {
        u16* base = smem;
        #pragma unroll
        for (int p = 0; p < 3; ++p) dma16(bbase[p], base + bdst[p]);
        if (tid < 256) dma16(abase[0], base + adst);
    }

    int kk1 = 0, s121 = 0;
    for (int s = 0; s < 36; ++s) {
        __syncthreads();
        if (s < 35) {
            if (++s121 == 12) { s121 = 0; ++kk1; }
            int koff = (s + 1) * 32;
            u16* base = smem + (((s + 1) & 1) ? DBO2 : 0);
            #pragma unroll
            for (int p = 0; p < 3; ++p) dma16(bbase[p] + koff, base + bdst[p]);
            if (tid < 256) dma16(abase[kk1] + s121 * 32, base + adst);
        }
        const u16* rb = smem + ((s & 1) ? DBO2 : 0);
        bf16x8 af0 = *(const bf16x8*)(rb + aoff[0]);
        bf16x8 af1 = *(const bf16x8*)(rb + aoff[1]);
        #pragma unroll
        for (int j = 0; j < 6; ++j) {
            bf16x8 bf = *(const bf16x8*)(rb + boff[j]);
            acc[0][j] = __builtin_amdgcn_mfma_f32_16x16x32_bf16(af0, bf, acc[0][j], 0, 0, 0);
            acc[1][j] = __builtin_amdgcn_mfma_f32_16x16x32_bf16(af1, bf, acc[1][j], 0, 0, 0);
        }
    }
    __syncthreads();
}

// ---------- kernel 2: GEMM1+LN+GELU (blocks 0..127) + expand (blocks 128..) ----------
__launch_bounds__(512)
__global__ void k_main1(const u16* __restrict__ xb, const u16* __restrict__ Wp,
                        const float* __restrict__ bias, const float* __restrict__ g,
                        const float* __restrict__ beta, u16* __restrict__ G,
                        const u16* __restrict__ zp, const float* __restrict__ x,
                        const int* __restrict__ tmap, float* __restrict__ out0) {
    __shared__ u16 smem[2 * DBO2];
    int tid = threadIdx.x;
    if (blockIdx.x >= 128) {
        // ---- expand: batched dependency chains ----
        int bi = blockIdx.x - 128;
        int v0 = bi * 4096;
        int tv[8];
        #pragma unroll
        for (int it = 0; it < 8; ++it) {
            int v = v0 + it * 512 + tid;
            tv[it] = tmap[v / 96];
        }
        uint4 val[8];
        #pragma unroll
        for (int it = 0; it < 8; ++it) {
            int v = v0 + it * 512 + tid;
            int c4 = v % 96;
            int b = (v / 96) >> 12;
            val[it] = make_uint4(0u, 0u, 0u, 0u);
            if (tv[it] >= 0)
                val[it] = *(const uint4*)(x + (size_t)((b << 9) + tv[it]) * H_ + c4 * 4);
        }
        #pragma unroll
        for (int it = 0; it < 8; ++it) {
            int v = v0 + it * 512 + tid;
            int row = v / 96, c4 = v % 96;
            *(uint4*)(out0 + (size_t)row * H_ + c4 * 4) = val[it];
        }
        return;
    }
    int w = tid >> 6, lane = tid & 63;
    int quad = lane >> 4, l16 = lane & 15;
    int wm = w & 1, wn = w >> 1;
    int m0 = blockIdx.x * 64;

    f32x4 acc[2][6];
    gemm_core32(smem, xb, Wp, zp, m0, tid, acc);

    float bcol[6], gcol[6], becol[6];
    #pragma unroll
    for (int j = 0; j < 6; ++j) {
        int col = wn * 96 + j * 16 + l16;
        bcol[j] = bias[col]; gcol[j] = g[col]; becol[j] = beta[col];
    }
    float* sb  = (float*)smem;          // [8][32]
    float* s2b = (float*)smem + 256;
    #pragma unroll
    for (int i = 0; i < 2; ++i)
        #pragma unroll
        for (int r = 0; r < 4; ++r) {
            float s = 0.f, s2 = 0.f;
            #pragma unroll
            for (int j = 0; j < 6; ++j) {
                float y = acc[i][j][r] + bcol[j];
                s += y; s2 += y * y;
            }
            #pragma unroll
            for (int off = 8; off; off >>= 1) { s += __shfl_down(s, off); s2 += __shfl_down(s2, off); }
            if (l16 == 0) {
                int rl = i * 16 + quad * 4 + r;       // [0,32)
                sb[(wm * 4 + wn) * 32 + rl] = s; s2b[(wm * 4 + wn) * 32 + rl] = s2;
            }
        }
    __syncthreads();
    #pragma unroll
    for (int i = 0; i < 2; ++i)
        #pragma unroll
        for (int r = 0; r < 4; ++r) {
            int rl = i * 16 + quad * 4 + r;
            float S = 0.f, S2 = 0.f;
            #pragma unroll
            for (int p = 0; p < 4; ++p) { S += sb[(wm * 4 + p) * 32 + rl]; S2 += s2b[(wm * 4 + p) * 32 + rl]; }
            float mean = S * (1.f / F_);
            float var  = S2 * (1.f / F_) - mean * mean;
            float rstd = rsqrtf(var + 1e-5f);
            #pragma unroll
            for (int j = 0; j < 6; ++j) {
                int col = wn * 96 + j * 16 + l16;
                float y  = (acc[i][j][r] + bcol[j] - mean) * rstd * gcol[j] + becol[j];
                float gl = 0.5f * y * (1.f + erff(y * 0.70710678118654752f));
                G[(size_t)(m0 + wm * 32 + rl) * F_ + col] = f2b(gl);
            }
        }
}

// ---------- kernel 3: GEMM2 + LN + GELU + dot(lw) + ReLU -> fp32 out1 ----------
__launch_bounds__(512)
__global__ void k_gemm2(const u16* __restrict__ G, const u16* __restrict__ Wp,
                        const float* __restrict__ bias, const float* __restrict__ g,
                        const float* __restrict__ beta, const float* __restrict__ lw,
                        const float* __restrict__ lb, float* __restrict__ out1,
                        const u16* __restrict__ zp) {
    __shared__ u16 smem[2 * DBO2];
    int tid = threadIdx.x;
    int w = tid >> 6, lane = tid & 63;
    int quad = lane >> 4, l16 = lane & 15;
    int wm = w & 1, wn = w >> 1;
    int m0 = blockIdx.x * 64;

    f32x4 acc[2][6];
    gemm_core32(smem, G, Wp, zp, m0, tid, acc);

    float bcol[6], gcol[6], becol[6], lwcol[6];
    #pragma unroll
    for (int j = 0; j < 6; ++j) {
        int col = wn * 96 + j * 16 + l16;
        bcol[j] = bias[col]; gcol[j] = g[col]; becol[j] = beta[col]; lwcol[j] = lw[col];
    }
    float* sb  = (float*)smem;          // [8][32]
    float* s2b = (float*)smem + 256;
    float* db  = (float*)smem + 512;
    #pragma unroll
    for (int i = 0; i < 2; ++i)
        #pragma unroll
        for (int r = 0; r < 4; ++r) {
            float s = 0.f, s2 = 0.f;
            #pragma unroll
            for (int j = 0; j < 6; ++j) {
                float y = acc[i][j][r] + bcol[j];
                s += y; s2 += y * y;
            }
            #pragma unroll
            for (int off = 8; off; off >>= 1) { s += __shfl_down(s, off); s2 += __shfl_down(s2, off); }
            if (l16 == 0) {
                int rl = i * 16 + quad * 4 + r;
                sb[(wm * 4 + wn) * 32 + rl] = s; s2b[(wm * 4 + wn) * 32 + rl] = s2;
            }
        }
    __syncthreads();
    #pragma unroll
    for (int i = 0; i < 2; ++i)
        #pragma unroll
        for (int r = 0; r < 4; ++r) {
            int rl = i * 16 + quad * 4 + r;
            float S = 0.f, S2 = 0.f;
            #pragma unroll
            for (int p = 0; p < 4; ++p) { S += sb[(wm * 4 + p) * 32 + rl]; S2 += s2b[(wm * 4 + p) * 32 + rl]; }
            float mean = S * (1.f / F_);
            float var  = S2 * (1.f / F_) - mean * mean;
            float rstd = rsqrtf(var + 1e-5f);
            float dot = 0.f;
            #pragma unroll
            for (int j = 0; j < 6; ++j) {
                float y  = (acc[i][j][r] + bcol[j] - mean) * rstd * gcol[j] + becol[j];
                float gl = 0.5f * y * (1.f + erff(y * 0.70710678118654752f));
                dot += gl * lwcol[j];
            }
            #pragma unroll
            for (int off = 8; off; off >>= 1) dot += __shfl_down(dot, off);
            if (l16 == 0) db[(wm * 4 + wn) * 32 + rl] = dot;
        }
    __syncthreads();
    if (tid < 64) {
        int wmv = tid >> 5, rl = tid & 31;
        float d = lb[0];
        #pragma unroll
        for (int p = 0; p < 4; ++p) d += db[(wmv * 4 + p) * 32 + rl];
        out1[m0 + tid] = fmaxf(d, 0.f);
    }
}

extern "C" void kernel_launch(void* const* d_in, const int* in_sizes, int n_in,
                              void* d_out, int out_size, void* d_ws, size_t ws_size,
                              hipStream_t stream) {
    const float* x   = (const float*)d_in[0];
    const float* td  = (const float*)d_in[1];
    const float* w1  = (const float*)d_in[2];
    const float* b1  = (const float*)d_in[3];
    const float* g1  = (const float*)d_in[4];
    const float* be1 = (const float*)d_in[5];
    const float* w2  = (const float*)d_in[6];
    const float* b2  = (const float*)d_in[7];
    const float* g2  = (const float*)d_in[8];
    const float* be2 = (const float*)d_in[9];
    const float* lw  = (const float*)d_in[10];
    const float* lb  = (const float*)d_in[11];

    float* out0 = (float*)d_out;                     // [B, L, H] fp32
    float* out1 = out0 + (size_t)B_ * L_ * H_;       // [B, T] fp32

    char* ws = (char*)d_ws;
    size_t off = 0;
    auto carve = [&](size_t bytes) -> void* {
        void* p = ws + off;
        off = (off + bytes + 255) & ~(size_t)255;
        return p;
    };
    int*  tmap = (int*)carve((size_t)B_ * L_ * sizeof(int));
    u16*  Wp1  = (u16*)carve((size_t)F_ * KD * sizeof(u16));
    u16*  Wp2  = (u16*)carve((size_t)F_ * KD * sizeof(u16));
    u16*  xb   = (u16*)carve((size_t)M_ * H_ * sizeof(u16));
    u16*  G    = (u16*)carve((size_t)M_ * F_ * sizeof(u16));
    u16*  zp   = (u16*)carve(1024);

    k_prep<<<3281, 512, 0, stream>>>(td, w1, w2, x, tmap, Wp1, Wp2, xb, zp);
    k_main1<<<128 + 1536, 512, 0, stream>>>(xb, Wp1, b1, g1, be1, G, zp, x, tmap, out0);
    k_gemm2<<<128, 512, 0, stream>>>(G, Wp2, b2, g2, be2, lw, lb, out1, zp);
}

// Round 13
// 181.423 us; speedup vs baseline: 1.0565x; 1.0565x over previous
//
#include <hip/hip_runtime.h>
#include <stdint.h>

typedef unsigned short u16;
typedef unsigned int   u32;

#define B_    16
#define T_    512
#define H_    384
#define F_    384
#define DMAX_ 8
#define L_    4096     // T_*DMAX_
#define KD    1152     // 3*H_
#define M_    8192     // B_*T_

typedef __bf16 bf16x8 __attribute__((ext_vector_type(8)));
typedef float  f32x4  __attribute__((ext_vector_type(4)));

typedef __attribute__((address_space(1))) u32 gu32;
typedef __attribute__((address_space(3))) u32 lu32;

__device__ __forceinline__ void dma16(const void* g, void* l) {
    __builtin_amdgcn_global_load_lds((gu32*)(uintptr_t)g, (lu32*)(u32)(uintptr_t)l, 16, 0, 0);
}

__device__ __forceinline__ u16 f2b(float f) {
    union { float f; u32 i; } v; v.f = f;
    u32 x = v.i;
    return (u16)((x + 0x7fffu + ((x >> 16) & 1u)) >> 16);   // RNE fp32->bf16
}

// =============== prep: durmap + zeropage + repack (coalesced) + xcast ===============
// grid: [0,16) durmap; 16 zp; [17,17+1728) repack; [1745,1745+1536) xcast. block=512.
__global__ void k_prep(const float* __restrict__ td, const float* __restrict__ w1,
                       const float* __restrict__ w2, const float* __restrict__ x,
                       int* __restrict__ tmap, u16* __restrict__ Wp1,
                       u16* __restrict__ Wp2, u16* __restrict__ xb,
                       u16* __restrict__ zp) {
    int blk = blockIdx.x, tid = threadIdx.x;
    if (blk < 16) {
        __shared__ int s[T_];
        int b = blk, t = tid;
        int d = (int)roundf(expf(td[b * T_ + t]));
        if (d < 0) d = 0; if (d > DMAX_) d = DMAX_;
        int v = d;
        s[t] = v;
        __syncthreads();
        for (int off = 1; off < T_; off <<= 1) {
            int add = (t >= off) ? s[t - off] : 0;
            __syncthreads();
            v += add;
            s[t] = v;
            __syncthreads();
        }
        int end = v, start = end - d;
        for (int i = start; i < end; ++i) tmap[b * L_ + i] = t;
        int total = s[T_ - 1];
        for (int l = total + t; l < L_; l += T_) tmap[b * L_ + l] = -1;
    } else if (blk == 16) {
        zp[tid] = 0;
    } else if (blk < 17 + 1728) {
        // dst-major: coalesced 2B writes, stride-3 reads (L2-absorbed)
        int i = (blk - 17) * 512 + tid;              // [0, 2*F*KD)
        const int n = F_ * KD;
        const float* src = (i < n) ? w1 : w2;
        u16* dst         = (i < n) ? Wp1 : Wp2;
        int ii = (i < n) ? i : i - n;
        int f = ii / KD;
        int rem = ii % KD;
        int kk = rem / H_, c = rem % H_;
        dst[ii] = f2b(src[f * KD + c * 3 + kk]);
    } else {
        int v = (blk - 1745) * 512 + tid;            // [0, M*96) float4 groups
        float4 f = *(const float4*)(x + (size_t)v * 4);
        u16 o[4] = { f2b(f.x), f2b(f.y), f2b(f.z), f2b(f.w) };
        *(uint2*)(xb + (size_t)v * 4) = *(uint2*)o;
    }
}

// =============== expand branch helper: batched dependency chains ===============
__device__ __forceinline__ void expand_block(const float* __restrict__ x,
                                             const int* __restrict__ tmap,
                                             float* __restrict__ out0,
                                             int v0, int tid) {
    int tv[8];
    #pragma unroll
    for (int it = 0; it < 8; ++it) {
        int v = v0 + it * 512 + tid;
        tv[it] = tmap[v / 96];
    }
    uint4 val[8];
    #pragma unroll
    for (int it = 0; it < 8; ++it) {
        int v = v0 + it * 512 + tid;
        int c4 = v % 96;
        int b = (v / 96) >> 12;
        val[it] = make_uint4(0u, 0u, 0u, 0u);
        if (tv[it] >= 0)
            val[it] = *(const uint4*)(x + (size_t)((b << 9) + tv[it]) * H_ + c4 * 4);
    }
    #pragma unroll
    for (int it = 0; it < 8; ++it) {
        int v = v0 + it * 512 + tid;
        int row = v / 96, c4 = v % 96;
        *(uint4*)(out0 + (size_t)row * H_ + c4 * 4) = val[it];
    }
}

// =============== GEMM core: BM=64, BN=384 (full F), BK=64, dbuf, 512 thr ===============
// Per buffer: A = chunks [0,512), B = chunks [512,3584). chunk c at elem offset c*8.
// (row,qp): q_log = qp ^ (row&7). dbuf stride DBO elems. 18 K-steps.
#define CHT 3584
#define DBO 28672   // CHT*8

__device__ __forceinline__ void gemm_core64(u16* smem, const u16* __restrict__ src,
                                            const u16* __restrict__ Wp,
                                            const u16* __restrict__ zp,
                                            int m0, int tid, f32x4 acc[2][6]) {
    int w = tid >> 6, lane = tid & 63;
    int quad = lane >> 4, l16 = lane & 15;
    int wm = w & 1, wn = w >> 1;

    // A staging: every thread stages one A chunk per step
    int rowA = tid >> 3;                       // [0,64)
    int qlA  = (tid & 7) ^ (rowA & 7);
    int arow = m0 + rowA;
    int bB = arow >> 9, tt = arow & 511;
    const u16* abase[3];
    #pragma unroll
    for (int kk = 0; kk < 3; ++kk) {
        int ts = tt + kk - 1;
        abase[kk] = (ts >= 0 && ts < T_) ? (src + (size_t)((bB << 9) + ts) * H_ + qlA * 8)
                                         : (zp + qlA * 8);
    }
    int adst = tid * 8;
    // B staging: 6 chunks/thread
    const u16* bbase[6];
    int bdst[6];
    #pragma unroll
    for (int p = 0; p < 6; ++p) {
        int idx = p * 512 + tid;               // [0,3072)
        int rowB = idx >> 3;                   // [0,384)
        int qlB  = (tid & 7) ^ (rowB & 7);
        bbase[p] = Wp + (size_t)rowB * KD + qlB * 8;
        bdst[p]  = (512 + idx) * 8;
    }

    // read offsets (elements)
    int aoff[2][2], boff[6][2];
    #pragma unroll
    for (int i = 0; i < 2; ++i)
        #pragma unroll
        for (int kv = 0; kv < 2; ++kv) {
            int row = wm * 32 + i * 16 + l16;
            aoff[i][kv] = ((row << 3) | ((kv * 4 + quad) ^ (row & 7))) * 8;
        }
    #pragma unroll
    for (int j = 0; j < 6; ++j)
        #pragma unroll
        for (int kv = 0; kv < 2; ++kv) {
            int row = wn * 96 + j * 16 + l16;
            boff[j][kv] = (512 + ((row << 3) | ((kv * 4 + quad) ^ (row & 7)))) * 8;
        }

    #pragma unroll
    for (int i = 0; i < 2; ++i)
        #pragma unroll
        for (int j = 0; j < 6; ++j)
            acc[i][j] = f32x4{0.f, 0.f, 0.f, 0.f};

    // stage step 0 -> buf 0
    {
        u16* base = smem;
        #pragma unroll
        for (int p = 0; p < 6; ++p) dma16(bbase[p], base + bdst[p]);
        dma16(abase[0], base + adst);
    }

    int kk1 = 0, s61 = 0;
    for (int s = 0; s < 18; ++s) {
        __syncthreads();
        if (s < 17) {
            if (++s61 == 6) { s61 = 0; ++kk1; }
            int koff = (s + 1) * 64;
            u16* base = smem + (((s + 1) & 1) ? DBO : 0);
            #pragma unroll
            for (int p = 0; p < 6; ++p) dma16(bbase[p] + koff, base + bdst[p]);
            dma16(abase[kk1] + s61 * 64, base + adst);
        }
        const u16* rb = smem + ((s & 1) ? DBO : 0);
        #pragma unroll
        for (int kv = 0; kv < 2; ++kv) {
            bf16x8 af0 = *(const bf16x8*)(rb + aoff[0][kv]);
            bf16x8 af1 = *(const bf16x8*)(rb + aoff[1][kv]);
            #pragma unroll
            for (int j = 0; j < 6; ++j) {
                bf16x8 bf = *(const bf16x8*)(rb + boff[j][kv]);
                acc[0][j] = __builtin_amdgcn_mfma_f32_16x16x32_bf16(af0, bf, acc[0][j], 0, 0, 0);
                acc[1][j] = __builtin_amdgcn_mfma_f32_16x16x32_bf16(af1, bf, acc[1][j], 0, 0, 0);
            }
        }
    }
    __syncthreads();
}

// ---------- kernel 2: GEMM1+LN+GELU (blocks 0..127) + expand 1st half (128..895) ----------
__launch_bounds__(512)
__global__ void k_main1(const u16* __restrict__ xb, const u16* __restrict__ Wp,
                        const float* __restrict__ bias, const float* __restrict__ g,
                        const float* __restrict__ beta, u16* __restrict__ G,
                        const u16* __restrict__ zp, const float* __restrict__ x,
                        const int* __restrict__ tmap, float* __restrict__ out0) {
    __shared__ u16 smem[2 * DBO];
    int tid = threadIdx.x;
    if (blockIdx.x >= 128) {
        expand_block(x, tmap, out0, (blockIdx.x - 128) * 4096, tid);
        return;
    }
    int w = tid >> 6, lane = tid & 63;
    int quad = lane >> 4, l16 = lane & 15;
    int wm = w & 1, wn = w >> 1;
    int m0 = blockIdx.x * 64;

    f32x4 acc[2][6];
    gemm_core64(smem, xb, Wp, zp, m0, tid, acc);

    float bcol[6], gcol[6], becol[6];
    #pragma unroll
    for (int j = 0; j < 6; ++j) {
        int col = wn * 96 + j * 16 + l16;
        bcol[j] = bias[col]; gcol[j] = g[col]; becol[j] = beta[col];
    }
    float* sb  = (float*)smem;          // [8][32]
    float* s2b = (float*)smem + 256;
    #pragma unroll
    for (int i = 0; i < 2; ++i)
        #pragma unroll
        for (int r = 0; r < 4; ++r) {
            float s = 0.f, s2 = 0.f;
            #pragma unroll
            for (int j = 0; j < 6; ++j) {
                float y = acc[i][j][r] + bcol[j];
                s += y; s2 += y * y;
            }
            #pragma unroll
            for (int off = 8; off; off >>= 1) { s += __shfl_down(s, off); s2 += __shfl_down(s2, off); }
            if (l16 == 0) {
                int rl = i * 16 + quad * 4 + r;       // [0,32)
                sb[(wm * 4 + wn) * 32 + rl] = s; s2b[(wm * 4 + wn) * 32 + rl] = s2;
            }
        }
    __syncthreads();
    #pragma unroll
    for (int i = 0; i < 2; ++i)
        #pragma unroll
        for (int r = 0; r < 4; ++r) {
            int rl = i * 16 + quad * 4 + r;
            float S = 0.f, S2 = 0.f;
            #pragma unroll
            for (int p = 0; p < 4; ++p) { S += sb[(wm * 4 + p) * 32 + rl]; S2 += s2b[(wm * 4 + p) * 32 + rl]; }
            float mean = S * (1.f / F_);
            float var  = S2 * (1.f / F_) - mean * mean;
            float rstd = rsqrtf(var + 1e-5f);
            #pragma unroll
            for (int j = 0; j < 6; ++j) {
                int col = wn * 96 + j * 16 + l16;
                float y  = (acc[i][j][r] + bcol[j] - mean) * rstd * gcol[j] + becol[j];
                float gl = 0.5f * y * (1.f + erff(y * 0.70710678118654752f));
                G[(size_t)(m0 + wm * 32 + rl) * F_ + col] = f2b(gl);
            }
        }
}

// ---------- kernel 3: GEMM2+LN+GELU+dot+ReLU (0..127) + expand 2nd half (128..895) ----------
__launch_bounds__(512)
__global__ void k_gemm2(const u16* __restrict__ G, const u16* __restrict__ Wp,
                        const float* __restrict__ bias, const float* __restrict__ g,
                        const float* __restrict__ beta, const float* __restrict__ lw,
                        const float* __restrict__ lb, float* __restrict__ out1,
                        const u16* __restrict__ zp, const float* __restrict__ x,
                        const int* __restrict__ tmap, float* __restrict__ out0) {
    __shared__ u16 smem[2 * DBO];
    int tid = threadIdx.x;
    if (blockIdx.x >= 128) {
        expand_block(x, tmap, out0, 3145728 + (blockIdx.x - 128) * 4096, tid);
        return;
    }
    int w = tid >> 6, lane = tid & 63;
    int quad = lane >> 4, l16 = lane & 15;
    int wm = w & 1, wn = w >> 1;
    int m0 = blockIdx.x * 64;

    f32x4 acc[2][6];
    gemm_core64(smem, G, Wp, zp, m0, tid, acc);

    float bcol[6], gcol[6], becol[6], lwcol[6];
    #pragma unroll
    for (int j = 0; j < 6; ++j) {
        int col = wn * 96 + j * 16 + l16;
        bcol[j] = bias[col]; gcol[j] = g[col]; becol[j] = beta[col]; lwcol[j] = lw[col];
    }
    float* sb  = (float*)smem;          // [8][32]
    float* s2b = (float*)smem + 256;
    float* db  = (float*)smem + 512;
    #pragma unroll
    for (int i = 0; i < 2; ++i)
        #pragma unroll
        for (int r = 0; r < 4; ++r) {
            float s = 0.f, s2 = 0.f;
            #pragma unroll
            for (int j = 0; j < 6; ++j) {
                float y = acc[i][j][r] + bcol[j];
                s += y; s2 += y * y;
            }
            #pragma unroll
            for (int off = 8; off; off >>= 1) { s += __shfl_down(s, off); s2 += __shfl_down(s2, off); }
            if (l16 == 0) {
                int rl = i * 16 + quad * 4 + r;
                sb[(wm * 4 + wn) * 32 + rl] = s; s2b[(wm * 4 + wn) * 32 + rl] = s2;
            }
        }
    __syncthreads();
    #pragma unroll
    for (int i = 0; i < 2; ++i)
        #pragma unroll
        for (int r = 0; r < 4; ++r) {
            int rl = i * 16 + quad * 4 + r;
            float S = 0.f, S2 = 0.f;
            #pragma unroll
            for (int p = 0; p < 4; ++p) { S += sb[(wm * 4 + p) * 32 + rl]; S2 += s2b[(wm * 4 + p) * 32 + rl]; }
            float mean = S * (1.f / F_);
            float var  = S2 * (1.f / F_) - mean * mean;
            float rstd = rsqrtf(var + 1e-5f);
            float dot = 0.f;
            #pragma unroll
            for (int j = 0; j < 6; ++j) {
                float y  = (acc[i][j][r] + bcol[j] - mean) * rstd * gcol[j] + becol[j];
                float gl = 0.5f * y * (1.f + erff(y * 0.70710678118654752f));
                dot += gl * lwcol[j];
            }
            #pragma unroll
            for (int off = 8; off; off >>= 1) dot += __shfl_down(dot, off);
            if (l16 == 0) db[(wm * 4 + wn) * 32 + rl] = dot;
        }
    __syncthreads();
    if (tid < 64) {
        int wmv = tid >> 5, rl = tid & 31;
        float d = lb[0];
        #pragma unroll
        for (int p = 0; p < 4; ++p) d += db[(wmv * 4 + p) * 32 + rl];
        out1[m0 + tid] = fmaxf(d, 0.f);
    }
}

extern "C" void kernel_launch(void* const* d_in, const int* in_sizes, int n_in,
                              void* d_out, int out_size, void* d_ws, size_t ws_size,
                              hipStream_t stream) {
    const float* x   = (const float*)d_in[0];
    const float* td  = (const float*)d_in[1];
    const float* w1  = (const float*)d_in[2];
    const float* b1  = (const float*)d_in[3];
    const float* g1  = (const float*)d_in[4];
    const float* be1 = (const float*)d_in[5];
    const float* w2  = (const float*)d_in[6];
    const float* b2  = (const float*)d_in[7];
    const float* g2  = (const float*)d_in[8];
    const float* be2 = (const float*)d_in[9];
    const float* lw  = (const float*)d_in[10];
    const float* lb  = (const float*)d_in[11];

    float* out0 = (float*)d_out;                     // [B, L, H] fp32
    float* out1 = out0 + (size_t)B_ * L_ * H_;       // [B, T] fp32

    char* ws = (char*)d_ws;
    size_t off = 0;
    auto carve = [&](size_t bytes) -> void* {
        void* p = ws + off;
        off = (off + bytes + 255) & ~(size_t)255;
        return p;
    };
    int*  tmap = (int*)carve((size_t)B_ * L_ * sizeof(int));
    u16*  Wp1  = (u16*)carve((size_t)F_ * KD * sizeof(u16));
    u16*  Wp2  = (u16*)carve((size_t)F_ * KD * sizeof(u16));
    u16*  xb   = (u16*)carve((size_t)M_ * H_ * sizeof(u16));
    u16*  G    = (u16*)carve((size_t)M_ * F_ * sizeof(u16));
    u16*  zp   = (u16*)carve(1024);

    k_prep<<<3281, 512, 0, stream>>>(td, w1, w2, x, tmap, Wp1, Wp2, xb, zp);
    k_main1<<<128 + 768, 512, 0, stream>>>(xb, Wp1, b1, g1, be1, G, zp, x, tmap, out0);
    k_gemm2<<<128 + 768, 512, 0, stream>>>(G, Wp2, b2, g2, be2, lw, lb, out1, zp, x, tmap, out0);
}